// Round 2
// baseline (116.445 us; speedup 1.0000x reference)
//
#include <hip/hip_runtime.h>

// Problem constants (fixed by the reference)
#define BATCH 32
#define NN    128                 // nodes
#define NIN   128                 // node features
#define NHID  256                 // hidden
#define NOUT  128                 // output features
#define ROWS  (BATCH * NN)        // 4096 flattened (b,n) rows

typedef __attribute__((ext_vector_type(2))) float f32x2;   // -> v_pk_*_f32

// ---------------------------------------------------------------------------
// K1: S[row,c] = x[row,:] @ W1[0:128, c]
//     R[row,c] = x[row,:] @ W1[128:256, c] + b1[c]
// 8 rows per block, 256 threads = one thread per hidden channel c.
// f32x2 accumulators -> v_pk_fma_f32 (2 FMA/instr), horizontal add at the end.
// ---------------------------------------------------------------------------
__global__ __launch_bounds__(256) void k1_sr(
    const float* __restrict__ x, const float* __restrict__ W1,
    const float* __restrict__ b1, float* __restrict__ S, float* __restrict__ R)
{
    __shared__ float xr[8][128];          // 4 KB
    const int row0 = blockIdx.x * 8;
    const int t = threadIdx.x;
    for (int idx = t; idx < 8 * 128; idx += 256)
        xr[idx >> 7][idx & 127] = x[(size_t)row0 * NIN + idx];
    __syncthreads();

    const int c = t;                      // 0..255
    f32x2 accs[8], accr[8];
#pragma unroll
    for (int r = 0; r < 8; ++r) { accs[r] = (f32x2)0.f; accr[r] = (f32x2)0.f; }

    for (int k = 0; k < NIN; k += 4) {
        f32x2 wa0, wa1, wb0, wb1;         // W1 column pairs (coalesced, L2-hot)
        wa0.x = W1[(size_t)(k+0)*NHID + c]; wa0.y = W1[(size_t)(k+1)*NHID + c];
        wa1.x = W1[(size_t)(k+2)*NHID + c]; wa1.y = W1[(size_t)(k+3)*NHID + c];
        wb0.x = W1[(size_t)(NIN+k+0)*NHID + c]; wb0.y = W1[(size_t)(NIN+k+1)*NHID + c];
        wb1.x = W1[(size_t)(NIN+k+2)*NHID + c]; wb1.y = W1[(size_t)(NIN+k+3)*NHID + c];
#pragma unroll
        for (int r = 0; r < 8; ++r) {
            const float4 xv = *(const float4*)(&xr[r][k]);   // ds_read_b128, wave-uniform
            f32x2 xlo; xlo.x = xv.x; xlo.y = xv.y;
            f32x2 xhi; xhi.x = xv.z; xhi.y = xv.w;
            accs[r] = __builtin_elementwise_fma(xlo, wa0, accs[r]);  // v_pk_fma_f32
            accs[r] = __builtin_elementwise_fma(xhi, wa1, accs[r]);
            accr[r] = __builtin_elementwise_fma(xlo, wb0, accr[r]);
            accr[r] = __builtin_elementwise_fma(xhi, wb1, accr[r]);
        }
    }
    const float bias = b1[c];
#pragma unroll
    for (int r = 0; r < 8; ++r) {
        S[(size_t)(row0 + r) * NHID + c] = accs[r].x + accs[r].y;
        R[(size_t)(row0 + r) * NHID + c] = accr[r].x + accr[r].y + bias;
    }
}

// ---------------------------------------------------------------------------
// K2 (fused): block (b, nt): 16 receivers, all 256 channels.
//   phase 1: G[n,c] = sum_{i != n} relu(S[b,i,c] + R[b,n,c])
//     computed as 0.5*(Ssum + 128*r + sum_i |s_i + r|) - relu(s_n + r):
//     per (i,q): v_pk_add_f32 (pairs of q) + v_add_f32 with free |abs|
//     input modifier -> ~1.6 VALU ops/element instead of 3.
//   phase 2: out[n,co] = (G[n,:] @ W2[:,co] + 127*b2[co]) / (127+1e-6)
//     v_pk_fma_f32 over k-pairs.
// LDS: 128 KB holds S[b][128][256]; front 16 KB reused for G transpose.
// Grid: 256 blocks (1/CU), 512 threads (8 waves/CU).
// ---------------------------------------------------------------------------
__global__ __launch_bounds__(512) void k2_fused(
    const float* __restrict__ S, const float* __restrict__ R,
    const float* __restrict__ W2, const float* __restrict__ b2,
    float* __restrict__ out)
{
    __shared__ float smem[128 * 256];     // 128 KB (gfx950 LDS = 160 KB/CU)

    const int blk = blockIdx.x;           // 0..255
    const int b   = blk >> 3;             // 0..31
    const int nt  = blk & 7;              // 0..7
    const int n0  = nt * 16;

    const int t = threadIdx.x;            // 0..511
    const int c = t & 255;                // channel
    const int h = t >> 8;                 // 0/1: 8-receiver half

    // ---- stage S[b]: 8192 float4, 16 per thread (coalesced)
    const float4* Sv  = (const float4*)(S + (size_t)b * NN * NHID);
    float4*       sm4 = (float4*)smem;
#pragma unroll
    for (int it = 0; it < 16; ++it)
        sm4[t + it * 512] = Sv[t + it * 512];
    __syncthreads();

    // ---- phase 1
    const int r0 = n0 + h * 8;
    float rv[8];
#pragma unroll
    for (int q = 0; q < 8; ++q)
        rv[q] = R[((size_t)(b * NN + r0 + q)) * NHID + c];   // coalesced

    f32x2 rv2[4], aab[4];
#pragma unroll
    for (int j = 0; j < 4; ++j) {
        rv2[j].x = rv[2*j]; rv2[j].y = rv[2*j+1];
        aab[j] = (f32x2)0.f;
    }
    float ssum = 0.f;

#pragma unroll 4
    for (int i = 0; i < NN; ++i) {
        const float s = smem[i * NHID + c];   // 64 consecutive floats/wave: free
        ssum += s;
        f32x2 s2; s2.x = s; s2.y = s;
#pragma unroll
        for (int j = 0; j < 4; ++j) {
            const f32x2 tj = s2 + rv2[j];            // v_pk_add_f32
            aab[j].x += __builtin_fabsf(tj.x);       // v_add_f32 with |abs| mod
            aab[j].y += __builtin_fabsf(tj.y);
        }
    }

    float gq[8];
#pragma unroll
    for (int q = 0; q < 8; ++q) {
        const float aa   = (q & 1) ? aab[q >> 1].y : aab[q >> 1].x;
        const float self = fmaxf(smem[(r0 + q) * NHID + c] + rv[q], 0.f);
        gq[q] = 0.5f * (ssum + 128.f * rv[q] + aa) - self;
    }

    __syncthreads();                      // all reads of S done
#pragma unroll
    for (int q = 0; q < 8; ++q)           // G transpose into front of smem
        smem[(h * 8 + q) * NHID + c] = gq[q];
    __syncthreads();

    // ---- phase 2: out = (G @ W2 + 127*b2) / (127 + 1e-6)
    const int co = t & 127;
    const int rg = t >> 7;                // 0..3, 4 rows each
    f32x2 a2[4];
#pragma unroll
    for (int r = 0; r < 4; ++r) a2[r] = (f32x2)0.f;

    for (int k = 0; k < NHID; k += 4) {
        f32x2 w0, w1;                     // W2 column pairs (coalesced, L1-hot)
        w0.x = W2[(size_t)(k+0)*NOUT + co]; w0.y = W2[(size_t)(k+1)*NOUT + co];
        w1.x = W2[(size_t)(k+2)*NOUT + co]; w1.y = W2[(size_t)(k+3)*NOUT + co];
#pragma unroll
        for (int r = 0; r < 4; ++r) {
            const float4 gv = *(const float4*)(&smem[(rg * 4 + r) * NHID + k]);
            f32x2 glo; glo.x = gv.x; glo.y = gv.y;
            f32x2 ghi; ghi.x = gv.z; ghi.y = gv.w;
            a2[r] = __builtin_elementwise_fma(glo, w0, a2[r]);  // v_pk_fma_f32
            a2[r] = __builtin_elementwise_fma(ghi, w1, a2[r]);
        }
    }
    const float inv  = 1.0f / (127.0f + 1e-6f);
    const float bias = 127.0f * b2[co];
#pragma unroll
    for (int r = 0; r < 4; ++r)
        out[((size_t)(b * NN + n0 + rg * 4 + r)) * NOUT + co] =
            (a2[r].x + a2[r].y + bias) * inv;
}

// ---------------------------------------------------------------------------
extern "C" void kernel_launch(void* const* d_in, const int* in_sizes, int n_in,
                              void* d_out, int out_size, void* d_ws, size_t ws_size,
                              hipStream_t stream)
{
    const float* x  = (const float*)d_in[0];
    // d_in[1] rel_type, d_in[2] rel_rec, d_in[3] rel_send: structurally fixed, unused
    const float* W1 = (const float*)d_in[4];
    const float* b1 = (const float*)d_in[5];
    const float* W2 = (const float*)d_in[6];
    const float* b2 = (const float*)d_in[7];
    float* out = (float*)d_out;

    float* S = (float*)d_ws;                       // 4096*256 f32 = 4 MB
    float* R = S + (size_t)ROWS * NHID;            // 4 MB   (total 8 MB of ws)

    k1_sr   <<<ROWS / 8,  256, 0, stream>>>(x, W1, b1, S, R);
    k2_fused<<<BATCH * 8, 512, 0, stream>>>(S, R, W2, b2, out);
}

// Round 3
// 114.180 us; speedup vs baseline: 1.0198x; 1.0198x over previous
//
#include <hip/hip_runtime.h>

// Problem constants (fixed by the reference)
#define BATCH 32
#define NN    128                 // nodes
#define NIN   128                 // node features
#define NHID  256                 // hidden
#define NOUT  128                 // output features
#define ROWS  (BATCH * NN)        // 4096 flattened (b,n) rows

typedef __attribute__((ext_vector_type(2))) float f32x2;   // -> v_pk_*_f32

// ---------------------------------------------------------------------------
// K1: S[row,c] = x[row,:] @ W1[0:128, c]
//     R[row,c] = x[row,:] @ W1[128:256, c] + b1[c]
// 16 rows per block (256 blocks, 512 threads): each W1 element amortized over
// 16 rows -> W1 L2 traffic halves vs the 8-row version (128 MB -> 64 MB).
// Thread: c = t&255, rh = t>>8 -> 8 rows each. 8 waves/CU (2/SIMD).
// ---------------------------------------------------------------------------
__global__ __launch_bounds__(512) void k1_sr(
    const float* __restrict__ x, const float* __restrict__ W1,
    const float* __restrict__ b1, float* __restrict__ S, float* __restrict__ R)
{
    __shared__ float xr[16][128];         // 8 KB
    const int row0 = blockIdx.x * 16;
    const int t = threadIdx.x;

    // stage x: 16*128 floats = 512 float4, exactly one per thread (coalesced)
    ((float4*)xr)[t] = ((const float4*)(x + (size_t)row0 * NIN))[t];
    __syncthreads();

    const int c  = t & 255;               // hidden channel
    const int rh = t >> 8;                // 0/1: row half (8 rows each)

    f32x2 accs[8], accr[8];
#pragma unroll
    for (int r = 0; r < 8; ++r) { accs[r] = (f32x2)0.f; accr[r] = (f32x2)0.f; }

    for (int k = 0; k < NIN; k += 4) {
        f32x2 wa0, wa1, wb0, wb1;         // W1 column pairs (coalesced, L1/L2-hot)
        wa0.x = W1[(size_t)(k+0)*NHID + c]; wa0.y = W1[(size_t)(k+1)*NHID + c];
        wa1.x = W1[(size_t)(k+2)*NHID + c]; wa1.y = W1[(size_t)(k+3)*NHID + c];
        wb0.x = W1[(size_t)(NIN+k+0)*NHID + c]; wb0.y = W1[(size_t)(NIN+k+1)*NHID + c];
        wb1.x = W1[(size_t)(NIN+k+2)*NHID + c]; wb1.y = W1[(size_t)(NIN+k+3)*NHID + c];
#pragma unroll
        for (int r = 0; r < 8; ++r) {
            const float4 xv = *(const float4*)(&xr[rh * 8 + r][k]);  // wave-uniform LDS broadcast
            f32x2 xlo; xlo.x = xv.x; xlo.y = xv.y;
            f32x2 xhi; xhi.x = xv.z; xhi.y = xv.w;
            accs[r] = __builtin_elementwise_fma(xlo, wa0, accs[r]);  // v_pk_fma_f32
            accs[r] = __builtin_elementwise_fma(xhi, wa1, accs[r]);
            accr[r] = __builtin_elementwise_fma(xlo, wb0, accr[r]);
            accr[r] = __builtin_elementwise_fma(xhi, wb1, accr[r]);
        }
    }
    const float bias = b1[c];
#pragma unroll
    for (int r = 0; r < 8; ++r) {
        const int row = row0 + rh * 8 + r;
        S[(size_t)row * NHID + c] = accs[r].x + accs[r].y;
        R[(size_t)row * NHID + c] = accr[r].x + accr[r].y + bias;
    }
}

// ---------------------------------------------------------------------------
// K2 (fused): block (b, nt): 16 receivers, all 256 channels.
//   phase 1: G[n,c] = 0.5*(Ssum + 128*r + sum_i |s_i + r|) - relu(s_n + r)
//   phase 2: out[n,co] = (G[n,:] @ W2[:,co] + 127*b2[co]) / (127+1e-6)
// LDS: sS 128 KB (S[b]) + sG 16 KB (G tile, own region -> one barrier saved).
// R loads hoisted above staging so their L2 latency hides under the stage.
// Grid: 256 blocks (1/CU), 512 threads (8 waves/CU).
// ---------------------------------------------------------------------------
__global__ __launch_bounds__(512) void k2_fused(
    const float* __restrict__ S, const float* __restrict__ R,
    const float* __restrict__ W2, const float* __restrict__ b2,
    float* __restrict__ out)
{
    __shared__ float sS[128 * 256];       // 128 KB
    __shared__ float sG[16 * 256];        // 16 KB (total 144 KB <= 160 KB/CU)

    const int blk = blockIdx.x;           // 0..255
    const int b   = blk >> 3;             // 0..31
    const int nt  = blk & 7;              // 0..7
    const int n0  = nt * 16;

    const int t = threadIdx.x;            // 0..511
    const int c = t & 255;                // channel
    const int h = t >> 8;                 // 0/1: 8-receiver half
    const int r0 = n0 + h * 8;

    // ---- hoisted R loads (independent of staging; hide latency under it)
    float rv[8];
#pragma unroll
    for (int q = 0; q < 8; ++q)
        rv[q] = R[((size_t)(b * NN + r0 + q)) * NHID + c];   // coalesced

    // ---- stage S[b]: 8192 float4, 16 per thread (coalesced)
    const float4* Sv  = (const float4*)(S + (size_t)b * NN * NHID);
    float4*       sm4 = (float4*)sS;
#pragma unroll
    for (int it = 0; it < 16; ++it)
        sm4[t + it * 512] = Sv[t + it * 512];
    __syncthreads();

    // ---- phase 1
    f32x2 rv2[4], aab[4];
#pragma unroll
    for (int j = 0; j < 4; ++j) {
        rv2[j].x = rv[2*j]; rv2[j].y = rv[2*j+1];
        aab[j] = (f32x2)0.f;
    }
    float ssum = 0.f;

#pragma unroll 4
    for (int i = 0; i < NN; ++i) {
        const float s = sS[i * NHID + c];    // 64 consecutive floats/wave: free
        ssum += s;
        f32x2 s2; s2.x = s; s2.y = s;
#pragma unroll
        for (int j = 0; j < 4; ++j) {
            const f32x2 tj = s2 + rv2[j];            // v_pk_add_f32
            aab[j].x += __builtin_fabsf(tj.x);       // v_add_f32 with |abs| mod
            aab[j].y += __builtin_fabsf(tj.y);
        }
    }

#pragma unroll
    for (int q = 0; q < 8; ++q) {
        const float aa   = (q & 1) ? aab[q >> 1].y : aab[q >> 1].x;
        const float self = fmaxf(sS[(r0 + q) * NHID + c] + rv[q], 0.f);
        sG[(h * 8 + q) * NHID + c] = 0.5f * (ssum + 128.f * rv[q] + aa) - self;
    }
    __syncthreads();                      // sG ready for all waves

    // ---- phase 2: out = (G @ W2 + 127*b2) / (127 + 1e-6)
    const int co = t & 127;
    const int rg = t >> 7;                // 0..3, 4 rows each
    f32x2 a2[4];
#pragma unroll
    for (int r = 0; r < 4; ++r) a2[r] = (f32x2)0.f;

    for (int k = 0; k < NHID; k += 4) {
        f32x2 w0, w1;                     // W2 column pairs (coalesced, L1-hot)
        w0.x = W2[(size_t)(k+0)*NOUT + co]; w0.y = W2[(size_t)(k+1)*NOUT + co];
        w1.x = W2[(size_t)(k+2)*NOUT + co]; w1.y = W2[(size_t)(k+3)*NOUT + co];
#pragma unroll
        for (int r = 0; r < 4; ++r) {
            const float4 gv = *(const float4*)(&sG[(rg * 4 + r) * NHID + k]);  // broadcast
            f32x2 glo; glo.x = gv.x; glo.y = gv.y;
            f32x2 ghi; ghi.x = gv.z; ghi.y = gv.w;
            a2[r] = __builtin_elementwise_fma(glo, w0, a2[r]);  // v_pk_fma_f32
            a2[r] = __builtin_elementwise_fma(ghi, w1, a2[r]);
        }
    }
    const float inv  = 1.0f / (127.0f + 1e-6f);
    const float bias = 127.0f * b2[co];
#pragma unroll
    for (int r = 0; r < 4; ++r)
        out[((size_t)(b * NN + n0 + rg * 4 + r)) * NOUT + co] =
            (a2[r].x + a2[r].y + bias) * inv;
}

// ---------------------------------------------------------------------------
extern "C" void kernel_launch(void* const* d_in, const int* in_sizes, int n_in,
                              void* d_out, int out_size, void* d_ws, size_t ws_size,
                              hipStream_t stream)
{
    const float* x  = (const float*)d_in[0];
    // d_in[1] rel_type, d_in[2] rel_rec, d_in[3] rel_send: structurally fixed, unused
    const float* W1 = (const float*)d_in[4];
    const float* b1 = (const float*)d_in[5];
    const float* W2 = (const float*)d_in[6];
    const float* b2 = (const float*)d_in[7];
    float* out = (float*)d_out;

    float* S = (float*)d_ws;                       // 4096*256 f32 = 4 MB
    float* R = S + (size_t)ROWS * NHID;            // 4 MB   (total 8 MB of ws)

    k1_sr   <<<ROWS / 16, 512, 0, stream>>>(x, W1, b1, S, R);
    k2_fused<<<BATCH * 8, 512, 0, stream>>>(S, R, W2, b2, out);
}